// Round 9
// baseline (218.213 us; speedup 1.0000x reference)
//
#include <hip/hip_runtime.h>
#include <hip/hip_bf16.h>

// MultiHeadAttention: B=2, S=2048, H=16, D=64, E=1024. f32 I/O, bf16 internal.
// R9 vs R8 (211us; attn FETCH fixed 131->12MB but time flat at 58 — attn is
// GRID-limited at 2 blocks/CU; GEMM K-loop changes neutral 3 rounds running,
// suspect scalar-store epilogues):
//  * attn: unpaired grid 1024 (one qt/block, LPT order, bh-per-XCD kept) ->
//    3 blocks/CU latency hiding.
//  * gemm_qkv + gemm_out: LDS-transpose epilogues -> 16B coalesced stores
//    (was 64 scalar 2B stores/thread on Q/K).

typedef __hip_bfloat16 bf16;
typedef __attribute__((ext_vector_type(8))) short bfrag;    // 8 bf16 = 4 VGPRs
typedef __attribute__((ext_vector_type(4))) float f32x4;
typedef __attribute__((ext_vector_type(16))) float f32x16;  // 32x32 C/D
typedef __attribute__((ext_vector_type(4))) short short4v;

#define MFMA16(a, b, c) __builtin_amdgcn_mfma_f32_16x16x32_bf16(a, b, c, 0, 0, 0)
#define MFMA32(a, b, c) __builtin_amdgcn_mfma_f32_32x32x16_bf16(a, b, c, 0, 0, 0)

// ---------------- fused cast + weight transposes --------------------------
// blocks 0..2047: x f32->bf16. 2048..2815: Wq/Wk/Wv -> WqkvT. 2816..3071: Wo.
__global__ __launch_bounds__(256) void prep_all(const float* __restrict__ x,
                                                const float* __restrict__ Wq,
                                                const float* __restrict__ Wk,
                                                const float* __restrict__ Wv,
                                                const float* __restrict__ Wo,
                                                bf16* __restrict__ xb,
                                                bf16* __restrict__ WqkvT,
                                                bf16* __restrict__ WoT) {
  __shared__ bf16 tile[64][80];
  int id = blockIdx.x;
  int t = threadIdx.x;
  if (id < 2048) {
    int i = id * 2048 + t * 8;
    float4 a = *(const float4*)(x + i);
    float4 b = *(const float4*)(x + i + 4);
    union { bf16 h[8]; bfrag v; } tmp;
    tmp.h[0] = __float2bfloat16(a.x); tmp.h[1] = __float2bfloat16(a.y);
    tmp.h[2] = __float2bfloat16(a.z); tmp.h[3] = __float2bfloat16(a.w);
    tmp.h[4] = __float2bfloat16(b.x); tmp.h[5] = __float2bfloat16(b.y);
    tmp.h[6] = __float2bfloat16(b.z); tmp.h[7] = __float2bfloat16(b.w);
    *(bfrag*)(xb + i) = tmp.v;
    return;
  }
  int wid = id - 2048;
  const float* src;
  bf16* dst;
  int srcld, dstld, r0, c0;
  if (wid < 768) {
    int w = wid >> 8, h = (wid >> 4) & 15;
    r0 = (wid & 15) * 64; c0 = 0;
    src = ((w == 0) ? Wq : (w == 1) ? Wk : Wv) + (long)h * 1024 * 64;
    dst = WqkvT + ((long)w * 1024 + h * 64) * 1024;
    srcld = 64; dstld = 1024;
  } else {
    int j = wid - 768;
    c0 = (j & 15) * 64; r0 = (j >> 4) * 64;
    src = Wo; dst = WoT;
    srcld = 1024; dstld = 1024;
  }
  int lr = t >> 3, lc = (t & 7) << 3;
#pragma unroll
  for (int p = 0; p < 2; ++p) {
    int r = lr + p * 32;
    const float* s = src + (long)(r0 + r) * srcld + c0 + lc;
    union { bf16 h8[8]; bfrag v; } tmp;
#pragma unroll
    for (int j = 0; j < 8; ++j) tmp.h8[j] = __float2bfloat16(s[j]);
    *(bfrag*)(&tile[r][lc]) = tmp.v;
  }
  __syncthreads();
#pragma unroll
  for (int p = 0; p < 2; ++p) {
    int c = lr + p * 32;
    union { bf16 h8[8]; bfrag v; } tmp;
#pragma unroll
    for (int j = 0; j < 8; ++j) tmp.h8[j] = tile[lc + j][c];
    *(bfrag*)(dst + (long)(c0 + c) * dstld + r0 + lc) = tmp.v;
  }
}

// ---------------- fused QKV GEMM: 128x128, BK=64, prefetch-2, XCD swizzle -
// Q/K head-major [b][h][s][d]; V [b][h][d][s]. LDS-transpose epilogue.
__global__ __launch_bounds__(256) void gemm_qkv128(const bf16* __restrict__ xb,
                                                   const bf16* __restrict__ WT,
                                                   const float* __restrict__ bq,
                                                   const float* __restrict__ bk,
                                                   const float* __restrict__ bv,
                                                   bf16* __restrict__ Q,
                                                   bf16* __restrict__ K_,
                                                   bf16* __restrict__ Vt) {
  const int K = 1024;
  __shared__ __align__(16) bf16 SH[2 * 128 * 72];   // K-loop: As|Bs; epi: T[128][136]
#define AS(r, c) SH[(r) * 72 + (c)]
#define BS(r, c) SH[9216 + (r) * 72 + (c)]
  int id = blockIdx.x;
  int xcd = id & 7, sw = id >> 3;
  int m0 = ((xcd << 2) | (sw & 3)) * 128;
  int n0 = (sw >> 2) * 128;
  int t = threadIdx.x, wave = t >> 6, lane = t & 63, quad = lane >> 4, col = lane & 15;
  int wr = (wave >> 1) * 64, wc = (wave & 1) * 64;
  f32x4 acc[4][4] = {};

  int srow = t >> 1, scol = (t & 1) * 32;
  const bf16* Ag = xb + (long)(m0 + srow) * K + scol;
  const bf16* Bg = WT + (long)(n0 + srow) * K + scol;

  bfrag A0[4], B0[4], A1[4], B1[4];
#pragma unroll
  for (int i = 0; i < 4; ++i) {
    A0[i] = *(const bfrag*)(Ag + 8 * i);
    B0[i] = *(const bfrag*)(Bg + 8 * i);
    A1[i] = *(const bfrag*)(Ag + 64 + 8 * i);
    B1[i] = *(const bfrag*)(Bg + 64 + 8 * i);
  }

  for (int k0 = 0; k0 < K; k0 += 64) {
    __syncthreads();
#pragma unroll
    for (int i = 0; i < 4; ++i) {
      *(bfrag*)(&AS(srow, scol + 8 * i)) = A0[i];
      *(bfrag*)(&BS(srow, scol + 8 * i)) = B0[i];
    }
    int kn = (k0 + 128 < K) ? k0 + 128 : K - 64;
#pragma unroll
    for (int i = 0; i < 4; ++i) {
      A0[i] = A1[i]; B0[i] = B1[i];
      A1[i] = *(const bfrag*)(Ag + kn + 8 * i);
      B1[i] = *(const bfrag*)(Bg + kn + 8 * i);
    }
    __syncthreads();
#pragma unroll
    for (int kc = 0; kc < 2; ++kc) {
      bfrag ra[4], rb[4];
#pragma unroll
      for (int i = 0; i < 4; ++i)
        ra[i] = *(const bfrag*)(&AS(wr + 16 * i + col, kc * 32 + quad * 8));
#pragma unroll
      for (int c = 0; c < 4; ++c)
        rb[c] = *(const bfrag*)(&BS(wc + 16 * c + col, kc * 32 + quad * 8));
#pragma unroll
      for (int c = 0; c < 4; ++c)
#pragma unroll
        for (int i = 0; i < 4; ++i) acc[c][i] = MFMA16(ra[i], rb[c], acc[c][i]);
    }
  }

  int sel = n0 >> 10;   // 0=Q, 1=K, 2=V
  const float* bias = (sel == 0) ? bq : (sel == 1) ? bk : bv;
  int blk_b = m0 >> 11, blk_s = m0 & 2047;        // constant within block
  __syncthreads();                                // K-loop LDS reads done

  if (sel < 2) {
    // T[m][n] stride 136: thread's 4 r-values are a column -> scalar writes
#pragma unroll
    for (int c = 0; c < 4; ++c) {
      int nl = wc + 16 * c + col;
      float bvv = bias[(n0 + nl) & 1023];
#pragma unroll
      for (int i = 0; i < 4; ++i) {
        int mb = wr + 16 * i + quad * 4;
#pragma unroll
        for (int r = 0; r < 4; ++r)
          SH[(mb + r) * 136 + nl] = __float2bfloat16(acc[c][i][r] + bvv);
      }
    }
    __syncthreads();
    // coalesced out: thread covers row m = t>>1, head-half (t&1)
    int m = t >> 1, half = t & 1;
    int h = (((n0 & 1023) >> 6) + half);
    bf16* dst = (sel == 0) ? Q : K_;
    bf16* p = dst + (((long)(blk_b * 16 + h)) * 2048 + blk_s + m) * 64;
#pragma unroll
    for (int j = 0; j < 8; ++j)
      *(bfrag*)(p + 8 * j) = *(const bfrag*)(&SH[m * 136 + half * 64 + 8 * j]);
  } else {
    // V: T[n][m] stride 136: thread's 4 r-values contiguous -> packed b64
#pragma unroll
    for (int c = 0; c < 4; ++c) {
      int nl = wc + 16 * c + col;
      float bvv = bias[(n0 + nl) & 1023];
#pragma unroll
      for (int i = 0; i < 4; ++i) {
        int mb = wr + 16 * i + quad * 4;
        union { bf16 h4[4]; short4v v; } pk;
#pragma unroll
        for (int r = 0; r < 4; ++r) pk.h4[r] = __float2bfloat16(acc[c][i][r] + bvv);
        *(short4v*)(&SH[nl * 136 + mb]) = pk.v;
      }
    }
    __syncthreads();
    int nl = t >> 1, mhalf = (t & 1) * 64;
    int h = ((n0 & 1023) + nl) >> 6, d = nl & 63;
    bf16* p = Vt + ((long)(blk_b * 16 + h) * 64 + d) * 2048 + blk_s + mhalf;
#pragma unroll
    for (int j = 0; j < 8; ++j)
      *(bfrag*)(p + 8 * j) = *(const bfrag*)(&SH[nl * 136 + mhalf + 8 * j]);
  }
#undef AS
#undef BS
}

// ---------------- out-projection: 128x64, BK=64, prefetch-2, XCD swizzle --
// A = O head-major [b][h][s][d]; k = h*64+d. LDS-transpose f32 epilogue.
__global__ __launch_bounds__(256) void gemm_out(const bf16* __restrict__ O,
                                                const bf16* __restrict__ Bt,
                                                float* __restrict__ Cf) {
  const int K = 1024;
  __shared__ __align__(16) char SHB[34816];       // K-loop 27648B | epi 128*68*4B
  bf16* SH = (bf16*)SHB;
#define AS(r, c) SH[(r) * 72 + (c)]
#define BS(r, c) SH[9216 + (r) * 72 + (c)]
  int id = blockIdx.x;
  int xcd = id & 7, sw = id >> 3;
  int m0 = ((xcd << 2) | (sw & 3)) * 128;
  int n0 = (sw >> 2) * 64;
  int t = threadIdx.x;
  int wave = t >> 6, lane = t & 63, quad = lane >> 4, col = lane & 15;
  int wr = (wave >> 1) * 64, wc = (wave & 1) * 32;
  f32x4 acc[2][4] = {};

  int srA = t >> 1, scA = (t & 1) * 32;
  int srB = t >> 2, scB = (t & 3) * 16;
  int mrow = m0 + srA;
  int ob = mrow >> 11, os = mrow & 2047;
  const bf16* Ag = O + (long)ob * 2097152 + (long)os * 64 + scA;
  const bf16* Bg = Bt + (long)(n0 + srB) * K + scB;

  bfrag A0[4], A1[4];
  bfrag B0[2], B1[2];
#pragma unroll
  for (int i = 0; i < 4; ++i) {
    A0[i] = *(const bfrag*)(Ag + 8 * i);
    A1[i] = *(const bfrag*)(Ag + (long)64 * 2048 + 8 * i);
  }
#pragma unroll
  for (int i = 0; i < 2; ++i) {
    B0[i] = *(const bfrag*)(Bg + 8 * i);
    B1[i] = *(const bfrag*)(Bg + 64 + 8 * i);
  }

  for (int k0 = 0; k0 < K; k0 += 64) {
    __syncthreads();
#pragma unroll
    for (int i = 0; i < 4; ++i) *(bfrag*)(&AS(srA, scA + 8 * i)) = A0[i];
#pragma unroll
    for (int i = 0; i < 2; ++i) *(bfrag*)(&BS(srB, scB + 8 * i)) = B0[i];
    int kn = (k0 + 128 < K) ? k0 + 128 : K - 64;
#pragma unroll
    for (int i = 0; i < 4; ++i) {
      A0[i] = A1[i];
      A1[i] = *(const bfrag*)(Ag + (long)kn * 2048 + 8 * i);
    }
#pragma unroll
    for (int i = 0; i < 2; ++i) {
      B0[i] = B1[i];
      B1[i] = *(const bfrag*)(Bg + kn + 8 * i);
    }
    __syncthreads();
#pragma unroll
    for (int kc = 0; kc < 2; ++kc) {
      bfrag ra[4], rb[2];
#pragma unroll
      for (int i = 0; i < 4; ++i)
        ra[i] = *(const bfrag*)(&AS(wr + 16 * i + col, kc * 32 + quad * 8));
#pragma unroll
      for (int c = 0; c < 2; ++c)
        rb[c] = *(const bfrag*)(&BS(wc + 16 * c + col, kc * 32 + quad * 8));
#pragma unroll
      for (int c = 0; c < 2; ++c)
#pragma unroll
        for (int i = 0; i < 4; ++i) acc[c][i] = MFMA16(ra[i], rb[c], acc[c][i]);
    }
  }

  __syncthreads();
  float* T = (float*)SHB;   // [128][68]
#pragma unroll
  for (int c = 0; c < 2; ++c) {
    int nl = wc + 16 * c + col;
#pragma unroll
    for (int i = 0; i < 4; ++i) {
      int mb = wr + 16 * i + quad * 4;
#pragma unroll
      for (int r = 0; r < 4; ++r) T[(mb + r) * 68 + nl] = acc[c][i][r];
    }
  }
  __syncthreads();
  int m = t >> 1, nhalf = (t & 1) * 32;
  float* p = Cf + (long)(m0 + m) * 1024 + n0 + nhalf;
#pragma unroll
  for (int j = 0; j < 8; ++j)
    *(float4*)(p + 4 * j) = *(const float4*)(&T[m * 68 + nhalf + 4 * j]);
#undef AS
#undef BS
}

// ---------------- flash attention, pipelined, unpaired grid 1024 ----------
// Q/K head-major [b][h][s][d]; Vt [b][h][d][s]; O head-major.
__global__ __launch_bounds__(256) void attn_kernel(const bf16* __restrict__ Q,
                                                   const bf16* __restrict__ K_,
                                                   const bf16* __restrict__ Vt,
                                                   bf16* __restrict__ O) {
  int id = blockIdx.x;             // 1024 blocks
  int xcd = id & 7, jj = id >> 3;  // jj 0..127 per XCD slot
  int qt = 31 - (jj >> 2);         // LPT: big q-tiles dispatched first
  int bh = ((jj & 3) << 3) | xcd;  // 4 bh per XCD (K/V 2MB < L2)

  __shared__ bf16 Ks[128][72];     // [j][d]
  __shared__ bf16 Vs[64][136];     // [d][j]
  __shared__ bf16 Ps[64][136];     // [q][j]; f32 scratch in epilogue

  int t = threadIdx.x, wave = t >> 6, lane = t & 63;
  int qh = wave >> 1, jh = wave & 1, hi = lane >> 5, l5 = lane & 31;

  const float SC2 = 0.18033688f;   // (1/8) * log2(e); p = exp2(s*SC2 - 16)

  int krow = t >> 3, kg = (t & 7) * 8;
  int vrow = t >> 4, vg = (t & 15) * 8;
  const bf16* Kbase = K_ + ((long)bh * 2048 + krow) * 64 + kg;
  const bf16* Vbase = Vt + ((long)bh * 64 + vrow) * 2048 + vg;

  int q0 = qt * 64;
  int nj = (qt >> 1) + 1;

  bfrag qa[4];
  const bf16* qp = Q + ((long)bh * 2048 + q0 + 32 * qh + l5) * 64 + hi * 8;
#pragma unroll
  for (int kd = 0; kd < 4; ++kd) qa[kd] = *(const bfrag*)(qp + kd * 16);

  f32x16 o0, o1;
  float lsum[16];
#pragma unroll
  for (int r = 0; r < 16; ++r) { o0[r] = 0.f; o1[r] = 0.f; lsum[r] = 0.f; }

  bfrag kreg[4], vreg[4];
#pragma unroll
  for (int i = 0; i < 4; ++i)
    kreg[i] = *(const bfrag*)(Kbase + (long)(32 * i) * 64);

  for (int jt = 0; jt < nj; ++jt) {
    int j0 = jt * 128;
    __syncthreads();
#pragma unroll
    for (int i = 0; i < 4; ++i)
      *(bfrag*)(&Ks[krow + 32 * i][kg]) = kreg[i];
    int jn = (jt + 1 < nj) ? (jt + 1) * 128 : jt * 128;
#pragma unroll
    for (int i = 0; i < 4; ++i)
      vreg[i] = *(const bfrag*)(Vbase + (long)(16 * i) * 2048 + j0);
#pragma unroll
    for (int i = 0; i < 4; ++i)
      kreg[i] = *(const bfrag*)(Kbase + (long)(jn + 32 * i) * 64);
    __syncthreads();

    f32x16 s0, s1;
#pragma unroll
    for (int r = 0; r < 16; ++r) { s0[r] = 0.f; s1[r] = 0.f; }
#pragma unroll
    for (int kd = 0; kd < 4; ++kd) {
      bfrag kb0 = *(const bfrag*)(&Ks[jh * 64 + l5][kd * 16 + hi * 8]);
      bfrag kb1 = *(const bfrag*)(&Ks[jh * 64 + 32 + l5][kd * 16 + hi * 8]);
      s0 = MFMA32(qa[kd], kb0, s0);
      s1 = MFMA32(qa[kd], kb1, s1);
    }

    bool lastT = (jt == nj - 1);
#pragma unroll
    for (int jb = 0; jb < 2; ++jb) {
      int j = j0 + jh * 64 + jb * 32 + l5;
#pragma unroll
      for (int r = 0; r < 16; ++r) {
        int qrow = (r & 3) + 8 * (r >> 2) + 4 * hi;
        float sv = jb ? s1[r] : s0[r];
        float p = __builtin_amdgcn_exp2f(fmaf(sv, SC2, -16.0f));
        if (lastT) p = (j <= q0 + 32 * qh + qrow) ? p : 0.f;
        lsum[r] += p;
        Ps[32 * qh + qrow][jh * 64 + jb * 32 + l5] = __float2bfloat16(p);
      }
    }
#pragma unroll
    for (int i = 0; i < 4; ++i)
      *(bfrag*)(&Vs[vrow + 16 * i][vg]) = vreg[i];
    __syncthreads();

#pragma unroll
    for (int kj = 0; kj < 4; ++kj) {
      bfrag pa = *(const bfrag*)(&Ps[32 * qh + l5][jh * 64 + kj * 16 + hi * 8]);
      bfrag vb0 = *(const bfrag*)(&Vs[l5][jh * 64 + kj * 16 + hi * 8]);
      bfrag vb1 = *(const bfrag*)(&Vs[32 + l5][jh * 64 + kj * 16 + hi * 8]);
      o0 = MFMA32(pa, vb0, o0);
      o1 = MFMA32(pa, vb1, o1);
    }
  }

#pragma unroll
  for (int off = 1; off < 32; off <<= 1)
#pragma unroll
    for (int r = 0; r < 16; ++r) lsum[r] += __shfl_xor(lsum[r], off, 64);

  __syncthreads();
  float* Osc = (float*)&Ps[0][0];        // [2 qh][32 q][68]
  float* Lsc = (float*)&Vs[0][0];        // [2 qh][32 q]
  if (jh == 1) {
#pragma unroll
    for (int r = 0; r < 16; ++r) {
      int qrow = (r & 3) + 8 * (r >> 2) + 4 * hi;
      Osc[(qh * 32 + qrow) * 68 + 0 * 32 + l5] = o0[r];
      Osc[(qh * 32 + qrow) * 68 + 1 * 32 + l5] = o1[r];
    }
    if (l5 == 0) {
#pragma unroll
      for (int r = 0; r < 16; ++r) {
        int qrow = (r & 3) + 8 * (r >> 2) + 4 * hi;
        Lsc[qh * 32 + qrow] = lsum[r];
      }
    }
  }
  __syncthreads();
  if (jh == 0) {
#pragma unroll
    for (int r = 0; r < 16; ++r) {
      int qrow = (r & 3) + 8 * (r >> 2) + 4 * hi;
      float inv = 1.f / (lsum[r] + Lsc[qh * 32 + qrow]);
      int iq = q0 + 32 * qh + qrow;
      float v0 = o0[r] + Osc[(qh * 32 + qrow) * 68 + 0 * 32 + l5];
      float v1 = o1[r] + Osc[(qh * 32 + qrow) * 68 + 1 * 32 + l5];
      O[((long)bh * 2048 + iq) * 64 + l5] = __float2bfloat16(v0 * inv);
      O[((long)bh * 2048 + iq) * 64 + 32 + l5] = __float2bfloat16(v1 * inv);
    }
  }
}

extern "C" void kernel_launch(void* const* d_in, const int* in_sizes, int n_in,
                              void* d_out, int out_size, void* d_ws, size_t ws_size,
                              hipStream_t stream) {
  const float* x  = (const float*)d_in[0];
  const float* Wq = (const float*)d_in[1];
  const float* bq = (const float*)d_in[2];
  const float* Wk = (const float*)d_in[3];
  const float* bk = (const float*)d_in[4];
  const float* Wv = (const float*)d_in[5];
  const float* bv = (const float*)d_in[6];
  const float* Wo = (const float*)d_in[7];
  float* out = (float*)d_out;

  bf16* ws = (bf16*)d_ws;
  const long MB1 = 1 << 20;
  bf16* WqkvT = ws + 0 * MB1;    // [3072][1024]
  bf16* WoT   = ws + 3 * MB1;
  bf16* Q     = ws + 4 * MB1;    // [b][h][s][d]
  bf16* K_    = ws + 8 * MB1;    // [b][h][s][d]
  bf16* Vt    = ws + 12 * MB1;   // [b][h][d][s]
  bf16* O     = ws + 16 * MB1;   // [b][h][s][d]
  bf16* xb    = ws + 20 * MB1;

  prep_all<<<3072, 256, 0, stream>>>(x, Wq, Wk, Wv, Wo, xb, WqkvT, WoT);
  gemm_qkv128<<<768, 256, 0, stream>>>(xb, WqkvT, bq, bk, bv, Q, K_, Vt);
  attn_kernel<<<1024, 256, 0, stream>>>(Q, K_, Vt, O);
  gemm_out<<<512, 256, 0, stream>>>(O, WoT, out);
}

// Round 10
// 202.315 us; speedup vs baseline: 1.0786x; 1.0786x over previous
//
#include <hip/hip_runtime.h>
#include <hip/hip_bf16.h>

// MultiHeadAttention: B=2, S=2048, H=16, D=64, E=1024. f32 I/O, bf16 internal.
// R10 vs R9 (218us; R9's LDS-transpose GEMM epilogues REGRESSED ~10us -> revert
// to R8 direct stores; attn still ~50% idle):
//  * attn: S^T dataflow. QK computed operand-swapped (S^T = MFMA32(Kfrag,Qfrag))
//    so P^T exits in C-layout with q-on-lanes/j-on-regs == PV's B-operand needs
//    (modulo a lane^32 half-register swap done with shfl_xor). Kills the Ps LDS
//    buffer (53248->35840 B => 4 blocks/CU), the P write+read traffic, and the
//    16-row shuffle-tree (lsum is now a per-lane scalar, one shfl_xor).
//  * GEMMs: R8 K-loops + direct-store epilogues, XCD swizzles, prefetch-2.

typedef __hip_bfloat16 bf16;
typedef __attribute__((ext_vector_type(8))) short bfrag;    // 8 bf16 = 4 VGPRs
typedef __attribute__((ext_vector_type(4))) float f32x4;
typedef __attribute__((ext_vector_type(16))) float f32x16;  // 32x32 C/D
typedef __attribute__((ext_vector_type(4))) short short4v;

#define MFMA16(a, b, c) __builtin_amdgcn_mfma_f32_16x16x32_bf16(a, b, c, 0, 0, 0)
#define MFMA32(a, b, c) __builtin_amdgcn_mfma_f32_32x32x16_bf16(a, b, c, 0, 0, 0)

__device__ __forceinline__ unsigned pkbf(float a, float b) {
  union { bf16 h[2]; unsigned u; } w;
  w.h[0] = __float2bfloat16(a);
  w.h[1] = __float2bfloat16(b);
  return w.u;
}

// ---------------- fused cast + weight transposes --------------------------
// blocks 0..2047: x f32->bf16. 2048..2815: Wq/Wk/Wv -> WqkvT. 2816..3071: Wo.
__global__ __launch_bounds__(256) void prep_all(const float* __restrict__ x,
                                                const float* __restrict__ Wq,
                                                const float* __restrict__ Wk,
                                                const float* __restrict__ Wv,
                                                const float* __restrict__ Wo,
                                                bf16* __restrict__ xb,
                                                bf16* __restrict__ WqkvT,
                                                bf16* __restrict__ WoT) {
  __shared__ bf16 tile[64][80];
  int id = blockIdx.x;
  int t = threadIdx.x;
  if (id < 2048) {
    int i = id * 2048 + t * 8;
    float4 a = *(const float4*)(x + i);
    float4 b = *(const float4*)(x + i + 4);
    union { bf16 h[8]; bfrag v; } tmp;
    tmp.h[0] = __float2bfloat16(a.x); tmp.h[1] = __float2bfloat16(a.y);
    tmp.h[2] = __float2bfloat16(a.z); tmp.h[3] = __float2bfloat16(a.w);
    tmp.h[4] = __float2bfloat16(b.x); tmp.h[5] = __float2bfloat16(b.y);
    tmp.h[6] = __float2bfloat16(b.z); tmp.h[7] = __float2bfloat16(b.w);
    *(bfrag*)(xb + i) = tmp.v;
    return;
  }
  int wid = id - 2048;
  const float* src;
  bf16* dst;
  int srcld, dstld, r0, c0;
  if (wid < 768) {
    int w = wid >> 8, h = (wid >> 4) & 15;
    r0 = (wid & 15) * 64; c0 = 0;
    src = ((w == 0) ? Wq : (w == 1) ? Wk : Wv) + (long)h * 1024 * 64;
    dst = WqkvT + ((long)w * 1024 + h * 64) * 1024;
    srcld = 64; dstld = 1024;
  } else {
    int j = wid - 768;
    c0 = (j & 15) * 64; r0 = (j >> 4) * 64;
    src = Wo; dst = WoT;
    srcld = 1024; dstld = 1024;
  }
  int lr = t >> 3, lc = (t & 7) << 3;
#pragma unroll
  for (int p = 0; p < 2; ++p) {
    int r = lr + p * 32;
    const float* s = src + (long)(r0 + r) * srcld + c0 + lc;
    union { bf16 h8[8]; bfrag v; } tmp;
#pragma unroll
    for (int j = 0; j < 8; ++j) tmp.h8[j] = __float2bfloat16(s[j]);
    *(bfrag*)(&tile[r][lc]) = tmp.v;
  }
  __syncthreads();
#pragma unroll
  for (int p = 0; p < 2; ++p) {
    int c = lr + p * 32;
    union { bf16 h8[8]; bfrag v; } tmp;
#pragma unroll
    for (int j = 0; j < 8; ++j) tmp.h8[j] = tile[lc + j][c];
    *(bfrag*)(dst + (long)(c0 + c) * dstld + r0 + lc) = tmp.v;
  }
}

// ---------------- fused QKV GEMM: 128x128, BK=64, prefetch-2, XCD swizzle -
// Q/K head-major [b][h][s][d]; V [b][h][d][s]. Direct-store epilogue (R8).
__global__ __launch_bounds__(256) void gemm_qkv128(const bf16* __restrict__ xb,
                                                   const bf16* __restrict__ WT,
                                                   const float* __restrict__ bq,
                                                   const float* __restrict__ bk,
                                                   const float* __restrict__ bv,
                                                   bf16* __restrict__ Q,
                                                   bf16* __restrict__ K_,
                                                   bf16* __restrict__ Vt) {
  const int K = 1024;
  __shared__ bf16 As[128][72];
  __shared__ bf16 Bs[128][72];
  int id = blockIdx.x;
  int xcd = id & 7, sw = id >> 3;
  int m0 = ((xcd << 2) | (sw & 3)) * 128;
  int n0 = (sw >> 2) * 128;
  int t = threadIdx.x, wave = t >> 6, lane = t & 63, quad = lane >> 4, col = lane & 15;
  int wr = (wave >> 1) * 64, wc = (wave & 1) * 64;
  f32x4 acc[4][4] = {};

  int srow = t >> 1, scol = (t & 1) * 32;
  const bf16* Ag = xb + (long)(m0 + srow) * K + scol;
  const bf16* Bg = WT + (long)(n0 + srow) * K + scol;

  bfrag A0[4], B0[4], A1[4], B1[4];
#pragma unroll
  for (int i = 0; i < 4; ++i) {
    A0[i] = *(const bfrag*)(Ag + 8 * i);
    B0[i] = *(const bfrag*)(Bg + 8 * i);
    A1[i] = *(const bfrag*)(Ag + 64 + 8 * i);
    B1[i] = *(const bfrag*)(Bg + 64 + 8 * i);
  }

  for (int k0 = 0; k0 < K; k0 += 64) {
    __syncthreads();
#pragma unroll
    for (int i = 0; i < 4; ++i) {
      *(bfrag*)(&As[srow][scol + 8 * i]) = A0[i];
      *(bfrag*)(&Bs[srow][scol + 8 * i]) = B0[i];
    }
    int kn = (k0 + 128 < K) ? k0 + 128 : K - 64;
#pragma unroll
    for (int i = 0; i < 4; ++i) {
      A0[i] = A1[i]; B0[i] = B1[i];
      A1[i] = *(const bfrag*)(Ag + kn + 8 * i);
      B1[i] = *(const bfrag*)(Bg + kn + 8 * i);
    }
    __syncthreads();
#pragma unroll
    for (int kc = 0; kc < 2; ++kc) {
      bfrag ra[4], rb[4];
#pragma unroll
      for (int i = 0; i < 4; ++i)
        ra[i] = *(const bfrag*)(&As[wr + 16 * i + col][kc * 32 + quad * 8]);
#pragma unroll
      for (int c = 0; c < 4; ++c)
        rb[c] = *(const bfrag*)(&Bs[wc + 16 * c + col][kc * 32 + quad * 8]);
#pragma unroll
      for (int c = 0; c < 4; ++c)
#pragma unroll
        for (int i = 0; i < 4; ++i) acc[c][i] = MFMA16(ra[i], rb[c], acc[c][i]);
    }
  }

  int sel = n0 >> 10;   // 0=Q, 1=K, 2=V
  const float* bias = (sel == 0) ? bq : (sel == 1) ? bk : bv;
#pragma unroll
  for (int c = 0; c < 4; ++c) {
    int nn = (n0 + wc + 16 * c + col) & 1023;
    float bvv = bias[nn];
    int h = nn >> 6, d = nn & 63;
#pragma unroll
    for (int i = 0; i < 4; ++i) {
      int mb = m0 + wr + 16 * i + quad * 4;
      int b = mb >> 11, s0 = mb & 2047;
      if (sel < 2) {
        bf16* dst = (sel == 0) ? Q : K_;
        long base = ((long)((b << 4) + h) * 2048 + s0) * 64 + d;
#pragma unroll
        for (int r = 0; r < 4; ++r)
          dst[base + (long)r * 64] = __float2bfloat16(acc[c][i][r] + bvv);
      } else {
        union { bf16 h4[4]; short4v v; } pk;
#pragma unroll
        for (int r = 0; r < 4; ++r) pk.h4[r] = __float2bfloat16(acc[c][i][r] + bvv);
        *(short4v*)(Vt + (long)(((b << 4) + h) * 64 + d) * 2048 + s0) = pk.v;
      }
    }
  }
}

// ---------------- out-projection: 128x64, BK=64, prefetch-2, XCD swizzle --
__global__ __launch_bounds__(256) void gemm_out(const bf16* __restrict__ O,
                                                const bf16* __restrict__ Bt,
                                                float* __restrict__ Cf) {
  const int K = 1024;
  __shared__ bf16 As[128][72];
  __shared__ bf16 Bs[64][72];
  int id = blockIdx.x;
  int xcd = id & 7, sw = id >> 3;
  int m0 = ((xcd << 2) | (sw & 3)) * 128;
  int n0 = (sw >> 2) * 64;
  int t = threadIdx.x;
  int wave = t >> 6, lane = t & 63, quad = lane >> 4, col = lane & 15;
  int wr = (wave >> 1) * 64, wc = (wave & 1) * 32;
  f32x4 acc[2][4] = {};

  int srA = t >> 1, scA = (t & 1) * 32;
  int srB = t >> 2, scB = (t & 3) * 16;
  int mrow = m0 + srA;
  int ob = mrow >> 11, os = mrow & 2047;
  const bf16* Ag = O + (long)ob * 2097152 + (long)os * 64 + scA;
  const bf16* Bg = Bt + (long)(n0 + srB) * K + scB;

  bfrag A0[4], A1[4];
  bfrag B0[2], B1[2];
#pragma unroll
  for (int i = 0; i < 4; ++i) {
    A0[i] = *(const bfrag*)(Ag + 8 * i);
    A1[i] = *(const bfrag*)(Ag + (long)64 * 2048 + 8 * i);
  }
#pragma unroll
  for (int i = 0; i < 2; ++i) {
    B0[i] = *(const bfrag*)(Bg + 8 * i);
    B1[i] = *(const bfrag*)(Bg + 64 + 8 * i);
  }

  for (int k0 = 0; k0 < K; k0 += 64) {
    __syncthreads();
#pragma unroll
    for (int i = 0; i < 4; ++i) *(bfrag*)(&As[srA][scA + 8 * i]) = A0[i];
#pragma unroll
    for (int i = 0; i < 2; ++i) *(bfrag*)(&Bs[srB][scB + 8 * i]) = B0[i];
    int kn = (k0 + 128 < K) ? k0 + 128 : K - 64;
#pragma unroll
    for (int i = 0; i < 4; ++i) {
      A0[i] = A1[i];
      A1[i] = *(const bfrag*)(Ag + (long)kn * 2048 + 8 * i);
    }
#pragma unroll
    for (int i = 0; i < 2; ++i) {
      B0[i] = B1[i];
      B1[i] = *(const bfrag*)(Bg + kn + 8 * i);
    }
    __syncthreads();
#pragma unroll
    for (int kc = 0; kc < 2; ++kc) {
      bfrag ra[4], rb[2];
#pragma unroll
      for (int i = 0; i < 4; ++i)
        ra[i] = *(const bfrag*)(&As[wr + 16 * i + col][kc * 32 + quad * 8]);
#pragma unroll
      for (int c = 0; c < 2; ++c)
        rb[c] = *(const bfrag*)(&Bs[wc + 16 * c + col][kc * 32 + quad * 8]);
#pragma unroll
      for (int c = 0; c < 2; ++c)
#pragma unroll
        for (int i = 0; i < 4; ++i) acc[c][i] = MFMA16(ra[i], rb[c], acc[c][i]);
    }
  }

#pragma unroll
  for (int c = 0; c < 2; ++c) {
    int n = n0 + wc + 16 * c + col;
#pragma unroll
    for (int i = 0; i < 4; ++i)
#pragma unroll
      for (int r = 0; r < 4; ++r) {
        int m = m0 + wr + 16 * i + quad * 4 + r;
        Cf[(long)m * 1024 + n] = acc[c][i][r];
      }
  }
}

// ---------------- flash attention: S^T dataflow, no P LDS -----------------
// Q/K head-major [b][h][s][d]; Vt [b][h][d][s]; O head-major.
// S^T = MFMA32(A=K_rows, B=Q_rows): C cols = q (lanes), rows = j (regs).
// P^T then feeds PV's B operand in-register (lane^32 half swap);
// O^T = MFMA32(A=V^T from Vs[d][j], B=P^T): cols = q, rows = d.
__global__ __launch_bounds__(256) void attn_kernel(const bf16* __restrict__ Q,
                                                   const bf16* __restrict__ K_,
                                                   const bf16* __restrict__ Vt,
                                                   bf16* __restrict__ O) {
  int id = blockIdx.x;             // 1024 blocks
  int xcd = id & 7, jj = id >> 3;
  int qt = 31 - (jj >> 2);         // LPT
  int bh = ((jj & 3) << 3) | xcd;  // 4 bh per XCD

  __shared__ bf16 Ks[128][72];     // [j][d]; f32 Osc[64][68] overlay in epilogue
  __shared__ bf16 Vs[64][136];     // [d][j]; Lsc + Of overlay in epilogue

  int t = threadIdx.x, wave = t >> 6, lane = t & 63;
  int qh = wave >> 1, jh = wave & 1, hi = lane >> 5, l5 = lane & 31;

  const float SC2 = 0.18033688f;   // (1/8)*log2(e); p = exp2(s*SC2 - 16)

  int krow = t >> 3, kg = (t & 7) * 8;
  int vrow = t >> 4, vg = (t & 15) * 8;
  const bf16* Kbase = K_ + ((long)bh * 2048 + krow) * 64 + kg;
  const bf16* Vbase = Vt + ((long)bh * 64 + vrow) * 2048 + vg;

  int q0 = qt * 64;
  int nj = (qt >> 1) + 1;
  int qi = q0 + 32 * qh + l5;      // this lane's global q index

  bfrag qa[4];
  const bf16* qp = Q + ((long)bh * 2048 + q0 + 32 * qh + l5) * 64 + hi * 8;
#pragma unroll
  for (int kd = 0; kd < 4; ++kd) qa[kd] = *(const bfrag*)(qp + kd * 16);

  f32x16 o0, o1;                   // O^T partials: rows d / d+32, col q
  float lsum = 0.f;                // per-lane: sum over this wave's j-half
#pragma unroll
  for (int r = 0; r < 16; ++r) { o0[r] = 0.f; o1[r] = 0.f; }

  bfrag kreg[4], vreg[4];
#pragma unroll
  for (int i = 0; i < 4; ++i)
    kreg[i] = *(const bfrag*)(Kbase + (long)(32 * i) * 64);

  for (int jt = 0; jt < nj; ++jt) {
    int j0 = jt * 128;
    __syncthreads();
#pragma unroll
    for (int i = 0; i < 4; ++i)
      *(bfrag*)(&Ks[krow + 32 * i][kg]) = kreg[i];
    int jn = (jt + 1 < nj) ? (jt + 1) * 128 : jt * 128;
#pragma unroll
    for (int i = 0; i < 4; ++i)
      vreg[i] = *(const bfrag*)(Vbase + (long)(16 * i) * 2048 + j0);
#pragma unroll
    for (int i = 0; i < 4; ++i)
      kreg[i] = *(const bfrag*)(Kbase + (long)(jn + 32 * i) * 64);
    __syncthreads();

    // S^T: per wave 64j (own half) x 32q. A = K rows, B = Q rows.
    f32x16 s0, s1;
#pragma unroll
    for (int r = 0; r < 16; ++r) { s0[r] = 0.f; s1[r] = 0.f; }
#pragma unroll
    for (int kd = 0; kd < 4; ++kd) {
      bfrag ka0 = *(const bfrag*)(&Ks[jh * 64 + l5][kd * 16 + hi * 8]);
      bfrag ka1 = *(const bfrag*)(&Ks[jh * 64 + 32 + l5][kd * 16 + hi * 8]);
      s0 = MFMA32(ka0, qa[kd], s0);
      s1 = MFMA32(ka1, qa[kd], s1);
    }

    bool lastT = (jt == nj - 1);
    // softmax in-register; pack P^T bf16 groups (g[jb][0..3] = r0-3,4-7,8-11,12-15)
    unsigned g[2][4][2];
#pragma unroll
    for (int jb = 0; jb < 2; ++jb) {
      float pv[16];
#pragma unroll
      for (int r = 0; r < 16; ++r) {
        int jl = (r & 3) + 8 * (r >> 2) + 4 * hi;        // j within 32-block
        int j = j0 + jh * 64 + jb * 32 + jl;
        float sv = jb ? s1[r] : s0[r];
        float p = __builtin_amdgcn_exp2f(fmaf(sv, SC2, -16.0f));
        if (lastT) p = (j <= qi) ? p : 0.f;
        lsum += p;
        pv[r] = p;
      }
#pragma unroll
      for (int gg = 0; gg < 4; ++gg) {
        g[jb][gg][0] = pkbf(pv[4 * gg], pv[4 * gg + 1]);
        g[jb][gg][1] = pkbf(pv[4 * gg + 2], pv[4 * gg + 3]);
      }
    }
#pragma unroll
    for (int i = 0; i < 4; ++i)
      *(bfrag*)(&Vs[vrow + 16 * i][vg]) = vreg[i];
    __syncthreads();

    // PV: O^T += V^T * P^T over own j-half
#pragma unroll
    for (int jb = 0; jb < 2; ++jb) {
#pragma unroll
      for (int c = 0; c < 2; ++c) {
        // B-frag jj0..7 for k-chunk c: uses groups 2c (r-lo) and 2c+1 (r-hi)
        unsigned a0 = g[jb][2 * c][0], a1 = g[jb][2 * c][1];
        unsigned b0 = g[jb][2 * c + 1][0], b1 = g[jb][2 * c + 1][1];
        unsigned sa0 = __shfl_xor((int)a0, 32, 64);
        unsigned sa1 = __shfl_xor((int)a1, 32, 64);
        unsigned sb0 = __shfl_xor((int)b0, 32, 64);
        unsigned sb1 = __shfl_xor((int)b1, 32, 64);
        union { unsigned u[4]; bfrag f; } pf;
        pf.u[0] = hi ? sb0 : a0;
        pf.u[1] = hi ? sb1 : a1;
        pf.u[2] = hi ? b0 : sa0;
        pf.u[3] = hi ? b1 : sa1;
        int kk = jh * 64 + jb * 32 + c * 16 + hi * 8;
        bfrag av0 = *(const bfrag*)(&Vs[l5][kk]);
        bfrag av1 = *(const bfrag*)(&Vs[32 + l5][kk]);
        o0 = MFMA32(av0, pf.f, o0);
        o1 = MFMA32(av1, pf.f, o1);
      }
    }
  }

  // combine hi-halves of lsum (same q, different j-sets)
  lsum += __shfl_xor(lsum, 32, 64);

  __syncthreads();   // all Ks/Vs reads done; overlay scratch
  float* Osc = (float*)&Ks[0][0];                    // [64 q][68 d]
  float* Lsc = (float*)&Vs[0][0];                    // [64 q]
  bf16* Of = (bf16*)((char*)&Vs[0][0] + 512);        // [64 q][72 d]
  int q = 32 * qh + l5;
  if (jh == 1) {
#pragma unroll
    for (int r = 0; r < 16; ++r) {
      int d = (r & 3) + 8 * (r >> 2) + 4 * hi;
      Osc[q * 68 + d] = o0[r];
      Osc[q * 68 + 32 + d] = o1[r];
    }
    if (hi == 0) Lsc[q] = lsum;
  }
  __syncthreads();
  if (jh == 0) {
    float inv = 1.f / (lsum + Lsc[q]);
#pragma unroll
    for (int r = 0; r < 16; ++r) {
      int d = (r & 3) + 8 * (r >> 2) + 4 * hi;
      Of[q * 72 + d] = __float2bfloat16((o0[r] + Osc[q * 68 + d]) * inv);
      Of[q * 72 + 32 + d] = __float2bfloat16((o1[r] + Osc[q * 68 + 32 + d]) * inv);
    }
  }
  __syncthreads();
  int row = t >> 2, off = (t & 3) * 16;
  bf16* po = O + ((long)bh * 2048 + q0 + row) * 64 + off;
  *(bfrag*)(po) = *(const bfrag*)(&Of[row * 72 + off]);
  *(bfrag*)(po + 8) = *(const bfrag*)(&Of[row * 72 + off + 8]);
}

extern "C" void kernel_launch(void* const* d_in, const int* in_sizes, int n_in,
                              void* d_out, int out_size, void* d_ws, size_t ws_size,
                              hipStream_t stream) {
  const float* x  = (const float*)d_in[0];
  const float* Wq = (const float*)d_in[1];
  const float* bq = (const float*)d_in[2];
  const float* Wk = (const float*)d_in[3];
  const float* bk = (const float*)d_in[4];
  const float* Wv = (const float*)d_in[5];
  const float* bv = (const float*)d_in[6];
  const float* Wo = (const float*)d_in[7];
  float* out = (float*)d_out;

  bf16* ws = (bf16*)d_ws;
  const long MB1 = 1 << 20;
  bf16* WqkvT = ws + 0 * MB1;    // [3072][1024]
  bf16* WoT   = ws + 3 * MB1;
  bf16* Q     = ws + 4 * MB1;    // [b][h][s][d]
  bf16* K_    = ws + 8 * MB1;    // [b][h][s][d]
  bf16* Vt    = ws + 12 * MB1;   // [b][h][d][s]
  bf16* O     = ws + 16 * MB1;   // [b][h][s][d]
  bf16* xb    = ws + 20 * MB1;

  prep_all<<<3072, 256, 0, stream>>>(x, Wq, Wk, Wv, Wo, xb, WqkvT, WoT);
  gemm_qkv128<<<768, 256, 0, stream>>>(xb, WqkvT, bq, bk, bv, Q, K_, Vt);
  attn_kernel<<<1024, 256, 0, stream>>>(Q, K_, Vt, O);
  gemm_out<<<512, 256, 0, stream>>>(O, WoT, out);
}